// Round 13
// baseline (258.174 us; speedup 1.0000x reference)
//
#include <hip/hip_runtime.h>
#include <hip/hip_fp16.h>
#include <hip/hip_cooperative_groups.h>

namespace cg = cooperative_groups;

#define NN 50000
#define EE 800000
#define DD 96

#define NBIN 196            // coarse bins of 256 dst nodes: bin = d >> 8
#define CE   4096           // edges per prep block
#define CB   196            // ceil(EE / CE) prep blocks (= grid of k_prep)
#define EPT2 16             // CE / 256 edges per thread

// Harness passes integer inputs as int32 — edge_index is const int* (2,E).
// Lessons: (r7) cross-XCD global atomics = memory-side full-line RMW ->
// LDS-only atomics + coalesced writes. (r8) single-block scans of >10K elems
// are ~60us latency holes -> per-bin parallel scans. (r10) gather traffic ~
// E*row_bytes -> fp16 staging. (r11) aggregate-then-transform fuses a layer.
// (r12) LDS-occupancy: W as fp16 in LDS. (r13) prep chain = 6 launches of
// us-scale kernels -> one cooperative kernel with grid.sync; gather unroll
// was register-serialized (VGPR=32) -> 8-wide with relaxed launch_bounds.

// ---- prep: hist -> row-scan -> base-scan -> scatter -> CSR -> cvt ---------
// One cooperative kernel, 196 blocks x 256 threads (all co-resident).

__global__ __launch_bounds__(256) void k_prep(const int* __restrict__ ei,
                                              int* __restrict__ histB,
                                              int* __restrict__ binTot,
                                              int* __restrict__ binbase,
                                              int* __restrict__ rp,
                                              float* __restrict__ dinv,
                                              int* __restrict__ col,
                                              int* __restrict__ packed,
                                              const float* __restrict__ x,
                                              __half* __restrict__ xh) {
    cg::grid_group grid = cg::this_grid();
    __shared__ int hist[NBIN];
    __shared__ int lofs[NBIN + 1];
    __shared__ int cur[NBIN];
    __shared__ int sstart[NBIN];
    __shared__ int buf[CE];
    __shared__ int sh[256];
    int t = threadIdx.x;
    int blk = blockIdx.x;
    int e0 = blk * CE;
    int nE = min(CE, EE - e0);

    // registers hold this chunk's edges across phases 1 and 4
    int s_[EPT2], d_[EPT2];
#pragma unroll
    for (int k = 0; k < EPT2; ++k) {
        int e = e0 + k * 256 + t;
        s_[k] = (e < EE) ? ei[e] : 0;
        d_[k] = (e < EE) ? ei[EE + e] : -1;
    }

    // ---- phase 1: per-chunk coarse histogram (bin-major layout) ----
    if (t < NBIN) hist[t] = 0;
    __syncthreads();
#pragma unroll
    for (int k = 0; k < EPT2; ++k)
        if (d_[k] >= 0) atomicAdd(&hist[d_[k] >> 8], 1);
    __syncthreads();
    if (t < NBIN) histB[t * CB + blk] = hist[t];
    grid.sync();

    // ---- phase 2: block blk scans histB row blk (within-bin chunk prefix) ----
    {
        int v = (t < CB) ? histB[blk * CB + t] : 0;
        sh[t] = v;
        __syncthreads();
        for (int off = 1; off < 256; off <<= 1) {
            int u = (t >= off) ? sh[t - off] : 0;
            __syncthreads();
            sh[t] += u;
            __syncthreads();
        }
        if (t < CB) histB[blk * CB + t] = sh[t] - v;
        if (t == 255) binTot[blk] = sh[255];
    }
    grid.sync();

    // ---- phase 3: block 0 scans 196 bin totals -> binbase ----
    if (blk == 0) {
        int v = (t < NBIN) ? binTot[t] : 0;
        sh[t] = v;
        __syncthreads();
        for (int off = 1; off < 256; off <<= 1) {
            int u = (t >= off) ? sh[t - off] : 0;
            __syncthreads();
            sh[t] += u;
            __syncthreads();
        }
        if (t < NBIN) binbase[t] = sh[t] - v;
        if (t == 0) binbase[NBIN] = EE;
    }
    grid.sync();

    // ---- phase 4: bin-scatter this chunk's edges into packed[] ----
    {
        int v = (t < NBIN) ? hist[t] : 0;   // hist preserved from phase 1
        sh[t] = v;
        __syncthreads();
        for (int off = 1; off < 256; off <<= 1) {
            int u = (t >= off) ? sh[t - off] : 0;
            __syncthreads();
            sh[t] += u;
            __syncthreads();
        }
        if (t < NBIN) {
            lofs[t] = sh[t] - v;
            cur[t] = sh[t] - v;
            sstart[t] = binbase[t] + histB[t * CB + blk];
        }
        if (t == 0) lofs[NBIN] = nE;
        __syncthreads();
#pragma unroll
        for (int k = 0; k < EPT2; ++k)
            if (d_[k] >= 0) {
                int b = d_[k] >> 8;
                int pos = atomicAdd(&cur[b], 1);
                buf[pos] = s_[k] | ((d_[k] & 0xFF) << 16);
            }
        __syncthreads();
        for (int i = t; i < nE; i += 256) {
            int blo = 0, bhi = NBIN;
            while (bhi - blo > 1) {
                int mid = (blo + bhi) >> 1;
                if (lofs[mid] <= i) blo = mid; else bhi = mid;
            }
            packed[sstart[blo] + (i - lofs[blo])] = buf[i];
        }
    }
    grid.sync();

    // ---- phase 5: block blk builds CSR for bin blk (owns its col window) ----
    {
        int base = binbase[blk];
        int n = binbase[blk + 1] - base;
        int* h256 = buf;          // reuse LDS
        int* cur2 = buf + 256;
        h256[t] = 0;
        __syncthreads();
        for (int i = t; i < n; i += 256)
            atomicAdd(&h256[(packed[base + i] >> 16) & 0xFF], 1);
        __syncthreads();
        int v = h256[t];
        sh[t] = v;
        __syncthreads();
        for (int off = 1; off < 256; off <<= 1) {
            int u = (t >= off) ? sh[t - off] : 0;
            __syncthreads();
            sh[t] += u;
            __syncthreads();
        }
        int ex = sh[t] - v;
        cur2[t] = ex;
        int node = blk * 256 + t;
        if (node <= NN) rp[node] = base + ex;
        if (node < NN) dinv[node] = rsqrtf((float)(v + 1));  // +1 self-loop
        __syncthreads();
        for (int i = t; i < n; i += 256) {
            int pv = packed[base + i];
            int pos = atomicAdd(&cur2[(pv >> 16) & 0xFF], 1);
            col[base + pos] = pv & 0xFFFF;
        }
    }
    grid.sync();

    // ---- phase 6: xh = fp16(dinv .* x), grid-stride over half8 chunks ----
    for (int i = blk * 256 + t; i < NN * 12; i += CB * 256) {
        int row = i / 12;
        float sc = dinv[row];
        const float4* xx = (const float4*)x;
        float4 f0 = xx[i * 2], f1 = xx[i * 2 + 1];
        __half h[8];
        h[0] = __float2half_rn(sc * f0.x); h[1] = __float2half_rn(sc * f0.y);
        h[2] = __float2half_rn(sc * f0.z); h[3] = __float2half_rn(sc * f0.w);
        h[4] = __float2half_rn(sc * f1.x); h[5] = __float2half_rn(sc * f1.y);
        h[6] = __float2half_rn(sc * f1.z); h[7] = __float2half_rn(sc * f1.w);
        ((uint4*)xh)[i] = *(uint4*)h;
    }
}

// ---- fused layer = gather(agg) -> LDS -> @W + b -> relu --------------------
// v[d] = dinv[d]*(sum_{s in in(d)} xh[s] + xh[d]);  out = relu(v @ W + b).
// FINAL=0: write acth[d] = fp16(dinv[d]*out). FINAL=1: write f32 out.
// W staged in LDS as fp16; 8-wide gather unroll for memory-level parallelism.

template <int FINAL>
__global__ __launch_bounds__(384, 4) void k_fused(const __half* __restrict__ xh,
                                                  const int* __restrict__ rp,
                                                  const int* __restrict__ col,
                                                  const float* __restrict__ dinv,
                                                  const float* __restrict__ W,
                                                  const float* __restrict__ b,
                                                  __half* __restrict__ acth,
                                                  float* __restrict__ outf) {
    __shared__ __half Wl[DD * DD];    // fp16 W, row-major (18432 B)
    __shared__ float Al[32][100];     // +4 pad (12800 B)
    int t = threadIdx.x;
    for (int i = t; i < DD * DD / 8; i += 384) {
        const float4* ww = (const float4*)W;
        float4 f0 = ww[i * 2], f1 = ww[i * 2 + 1];
        __half h[8];
        h[0] = __float2half_rn(f0.x); h[1] = __float2half_rn(f0.y);
        h[2] = __float2half_rn(f0.z); h[3] = __float2half_rn(f0.w);
        h[4] = __float2half_rn(f1.x); h[5] = __float2half_rn(f1.y);
        h[6] = __float2half_rn(f1.z); h[7] = __float2half_rn(f1.w);
        ((uint4*)Wl)[i] = *(uint4*)h;
    }

    int c  = t % 12;                  // half8 column
    int ny = t / 12;                  // 0..31
    int d = blockIdx.x * 32 + ny;
    const uint4* h4 = (const uint4*)xh;   // row stride 12

    if (d < NN) {
        union U { uint4 u; __half2 h[4]; };
        float2 aA[4] = {{0,0},{0,0},{0,0},{0,0}};
        float2 aB[4] = {{0,0},{0,0},{0,0},{0,0}};
        int j0 = rp[d], j1 = rp[d + 1];
        int j = j0;
        for (; j + 7 < j1; j += 8) {     // 8 independent 16B loads in flight
            int s0 = col[j],   s1 = col[j+1], s2 = col[j+2], s3 = col[j+3];
            int s4 = col[j+4], s5 = col[j+5], s6 = col[j+6], s7 = col[j+7];
            U v0, v1, v2, v3, v4, v5, v6, v7;
            v0.u = h4[s0 * 12 + c];
            v1.u = h4[s1 * 12 + c];
            v2.u = h4[s2 * 12 + c];
            v3.u = h4[s3 * 12 + c];
            v4.u = h4[s4 * 12 + c];
            v5.u = h4[s5 * 12 + c];
            v6.u = h4[s6 * 12 + c];
            v7.u = h4[s7 * 12 + c];
#pragma unroll
            for (int k = 0; k < 4; ++k) {
                float2 f0 = __half22float2(v0.h[k]);
                float2 f1 = __half22float2(v1.h[k]);
                float2 f2 = __half22float2(v2.h[k]);
                float2 f3 = __half22float2(v3.h[k]);
                float2 f4 = __half22float2(v4.h[k]);
                float2 f5 = __half22float2(v5.h[k]);
                float2 f6 = __half22float2(v6.h[k]);
                float2 f7 = __half22float2(v7.h[k]);
                aA[k].x += (f0.x + f1.x) + (f4.x + f5.x);
                aA[k].y += (f0.y + f1.y) + (f4.y + f5.y);
                aB[k].x += (f2.x + f3.x) + (f6.x + f7.x);
                aB[k].y += (f2.y + f3.y) + (f6.y + f7.y);
            }
        }
        for (; j + 3 < j1; j += 4) {
            int s0 = col[j], s1 = col[j+1], s2 = col[j+2], s3 = col[j+3];
            U v0, v1, v2, v3;
            v0.u = h4[s0 * 12 + c];
            v1.u = h4[s1 * 12 + c];
            v2.u = h4[s2 * 12 + c];
            v3.u = h4[s3 * 12 + c];
#pragma unroll
            for (int k = 0; k < 4; ++k) {
                float2 f0 = __half22float2(v0.h[k]);
                float2 f1 = __half22float2(v1.h[k]);
                float2 f2 = __half22float2(v2.h[k]);
                float2 f3 = __half22float2(v3.h[k]);
                aA[k].x += f0.x + f1.x; aA[k].y += f0.y + f1.y;
                aB[k].x += f2.x + f3.x; aB[k].y += f2.y + f3.y;
            }
        }
        for (; j < j1; ++j) {
            U v; v.u = h4[col[j] * 12 + c];
#pragma unroll
            for (int k = 0; k < 4; ++k) {
                float2 f = __half22float2(v.h[k]);
                aA[k].x += f.x; aA[k].y += f.y;
            }
        }
        U self; self.u = h4[d * 12 + c];    // self-loop (pre-scaled by dinv[d])
        float dd = dinv[d];
        float v[8];
#pragma unroll
        for (int k = 0; k < 4; ++k) {
            float2 fs = __half22float2(self.h[k]);
            v[2*k]   = dd * (aA[k].x + aB[k].x + fs.x);
            v[2*k+1] = dd * (aA[k].y + aB[k].y + fs.y);
        }
        *(float4*)&Al[ny][c * 8]     = make_float4(v[0], v[1], v[2], v[3]);
        *(float4*)&Al[ny][c * 8 + 4] = make_float4(v[4], v[5], v[6], v[7]);
    }
    __syncthreads();

    // Phase B: out_tile = Al @ W + b, relu, write.
    int tx = t % 24;                  // col4 group
    int ry = t / 24;                  // rows ry, ry+16
    int c0 = tx * 4;
    float a0x = 0.f, a0y = 0.f, a0z = 0.f, a0w = 0.f;
    float a1x = 0.f, a1y = 0.f, a1z = 0.f, a1w = 0.f;
#pragma unroll 8
    for (int k = 0; k < DD; ++k) {
        uint2 wv = *(const uint2*)&Wl[k * DD + c0];   // 4 halves
        const __half2* wh = (const __half2*)&wv;
        float2 w01 = __half22float2(wh[0]);
        float2 w23 = __half22float2(wh[1]);
        float r0 = Al[ry][k];
        float r1 = Al[ry + 16][k];
        a0x += r0 * w01.x; a0y += r0 * w01.y; a0z += r0 * w23.x; a0w += r0 * w23.y;
        a1x += r1 * w01.x; a1y += r1 * w01.y; a1z += r1 * w23.x; a1w += r1 * w23.y;
    }
    float4 bb = *(const float4*)&b[c0];
    int g0 = blockIdx.x * 32 + ry;
    int g1 = g0 + 16;
    float r0x = fmaxf(a0x + bb.x, 0.f), r0y = fmaxf(a0y + bb.y, 0.f);
    float r0z = fmaxf(a0z + bb.z, 0.f), r0w = fmaxf(a0w + bb.w, 0.f);
    float r1x = fmaxf(a1x + bb.x, 0.f), r1y = fmaxf(a1y + bb.y, 0.f);
    float r1z = fmaxf(a1z + bb.z, 0.f), r1w = fmaxf(a1w + bb.w, 0.f);
    if (g0 < NN) {
        if (FINAL) {
            *(float4*)&outf[g0 * DD + c0] = make_float4(r0x, r0y, r0z, r0w);
        } else {
            float sc = dinv[g0];
            __half h[4];
            h[0] = __float2half_rn(sc * r0x); h[1] = __float2half_rn(sc * r0y);
            h[2] = __float2half_rn(sc * r0z); h[3] = __float2half_rn(sc * r0w);
            *(uint2*)&acth[g0 * DD + c0] = *(uint2*)h;
        }
    }
    if (g1 < NN) {
        if (FINAL) {
            *(float4*)&outf[g1 * DD + c0] = make_float4(r1x, r1y, r1z, r1w);
        } else {
            float sc = dinv[g1];
            __half h[4];
            h[0] = __float2half_rn(sc * r1x); h[1] = __float2half_rn(sc * r1y);
            h[2] = __float2half_rn(sc * r1z); h[3] = __float2half_rn(sc * r1w);
            *(uint2*)&acth[g1 * DD + c0] = *(uint2*)h;
        }
    }
}

// ----------------------------------------------------------------------------

extern "C" void kernel_launch(void* const* d_in, const int* in_sizes, int n_in,
                              void* d_out, int out_size, void* d_ws, size_t ws_size,
                              hipStream_t stream) {
    const float* x  = (const float*)d_in[0];
    const int*   ei = (const int*)d_in[1];
    const float* W1 = (const float*)d_in[2];
    const float* b1 = (const float*)d_in[3];
    const float* W2 = (const float*)d_in[4];
    const float* b2 = (const float*)d_in[5];
    float* out = (float*)d_out;

    // Workspace (~23.0 MB): histB, binTot, binbase, rp, dinv, col, bufA, bufB.
    // packed[] aliases bufA (EE ints = 3.2 MB <= 9.6 MB; dead before phase 6).
    char* p = (char*)d_ws;
    int*   histB   = (int*)p;   p += ((size_t)NBIN * CB * 4 + 255) & ~(size_t)255;
    int*   binTot  = (int*)p;   p += ((size_t)NBIN * 4 + 255) & ~(size_t)255;
    int*   binbase = (int*)p;   p += ((size_t)(NBIN + 1) * 4 + 255) & ~(size_t)255;
    int*   rp      = (int*)p;   p += ((size_t)(NN + 1) * 4 + 255) & ~(size_t)255;
    float* dinv    = (float*)p; p += ((size_t)NN * 4 + 255) & ~(size_t)255;
    int*   col     = (int*)p;   p += ((size_t)EE * 4 + 255) & ~(size_t)255;
    __half* bufA   = (__half*)p; p += ((size_t)NN * DD * 2 + 255) & ~(size_t)255;
    __half* bufB   = (__half*)p;                  // N*D halves (9.6 MB)
    int*   packed  = (int*)bufA;                  // EE ints, alias

    // ---- prep: whole CSR build + cvt in one cooperative kernel ----
    void* args[] = {(void*)&ei, (void*)&histB, (void*)&binTot, (void*)&binbase,
                    (void*)&rp, (void*)&dinv, (void*)&col, (void*)&packed,
                    (void*)&x, (void*)&bufA};
    hipLaunchCooperativeKernel((const void*)k_prep, dim3(CB), dim3(256),
                               args, 0, stream);

    // ---- layer 1 (fused): bufB = fp16(dinv .* relu(agg(bufA) @ W1 + b1)) ----
    k_fused<0><<<(NN + 31) / 32, 384, 0, stream>>>(bufA, rp, col, dinv, W1, b1,
                                                   bufB, nullptr);

    // ---- layer 2 (fused): d_out = relu(agg(bufB) @ W2 + b2) ----
    k_fused<1><<<(NN + 31) / 32, 384, 0, stream>>>(bufB, rp, col, dinv, W2, b2,
                                                   nullptr, out);
}

// Round 14
// 146.416 us; speedup vs baseline: 1.7633x; 1.7633x over previous
//
#include <hip/hip_runtime.h>
#include <hip/hip_fp16.h>

#define NN 50000
#define EE 800000
#define DD 96

#define NBIN 196            // coarse bins of 256 dst nodes: bin = d >> 8
#define CE   4096           // edges per phase-1 block
#define CB   196            // ceil(EE / CE) phase-1 blocks
#define EPT2 16             // CE / 256 edges per thread

// Harness passes integer inputs as int32 — edge_index is const int* (2,E).
// Lessons: (r7) cross-XCD global atomics = memory-side full-line RMW ->
// LDS-only atomics + coalesced writes. (r8) single-block scans of >10K elems
// are ~60us latency holes -> per-bin parallel scans. (r10) gather traffic ~
// E*row_bytes -> fp16 staging. (r11) aggregate-then-transform fuses a layer.
// (r12) LDS-occupancy: W as fp16 in LDS. (r13) cooperative prep fusion caps
// the whole chain at 196-block width + cross-XCD grid.sync cost -> 141us;
// mixed-width us-scale chains stay separate launches.

// ---- 1a: coarse histogram per edge-chunk --------------------------------

__global__ __launch_bounds__(256) void k_hist(const int* __restrict__ ei,
                                              int* __restrict__ histB) {
    __shared__ int hist[NBIN];
    int t = threadIdx.x;
    if (t < NBIN) hist[t] = 0;
    __syncthreads();
    int e0 = blockIdx.x * CE;
#pragma unroll
    for (int k = 0; k < EPT2; ++k) {
        int e = e0 + k * 256 + t;
        if (e < EE) atomicAdd(&hist[ei[EE + e] >> 8], 1);
    }
    __syncthreads();
    if (t < NBIN) histB[t * CB + blockIdx.x] = hist[t];  // bin-major
}

// ---- 1b-i: per-bin row scan (196 blocks, one row each) ------------------

__global__ __launch_bounds__(256) void k_scan_bins(int* __restrict__ histB,
                                                   int* __restrict__ binTot) {
    __shared__ int sh[256];
    int t = threadIdx.x;
    int b = blockIdx.x;
    int v = (t < CB) ? histB[b * CB + t] : 0;
    sh[t] = v;
    __syncthreads();
    for (int off = 1; off < 256; off <<= 1) {
        int u = (t >= off) ? sh[t - off] : 0;
        __syncthreads();
        sh[t] += u;
        __syncthreads();
    }
    if (t < CB) histB[b * CB + t] = sh[t] - v;   // exclusive within bin
    if (t == 255) binTot[b] = sh[255];           // bin total
}

// ---- 1b-ii: scan of 196 bin totals -> binbase ---------------------------

__global__ __launch_bounds__(256) void k_scan_tot(const int* __restrict__ binTot,
                                                  int* __restrict__ binbase) {
    __shared__ int sh[256];
    int t = threadIdx.x;
    int v = (t < NBIN) ? binTot[t] : 0;
    sh[t] = v;
    __syncthreads();
    for (int off = 1; off < 256; off <<= 1) {
        int u = (t >= off) ? sh[t - off] : 0;
        __syncthreads();
        sh[t] += u;
        __syncthreads();
    }
    if (t < NBIN) binbase[t] = sh[t] - v;
    if (t == 0) binbase[NBIN] = EE;
}

// ---- 1c: bin-scatter into packed[] (LDS sort, coalesced run writes) -----

__global__ __launch_bounds__(256) void k_scatter_bins(const int* __restrict__ ei,
                                                      const int* __restrict__ histB,
                                                      const int* __restrict__ binbase,
                                                      int* __restrict__ packed) {
    __shared__ int hist[NBIN];
    __shared__ int lofs[NBIN + 1];
    __shared__ int cur[NBIN];
    __shared__ int sstart[NBIN];
    __shared__ int buf[CE];
    __shared__ int sh[256];
    int t = threadIdx.x;
    int e0 = blockIdx.x * CE;
    int nE = min(CE, EE - e0);

    int s[EPT2], d[EPT2];
#pragma unroll
    for (int k = 0; k < EPT2; ++k) {
        int e = e0 + k * 256 + t;
        s[k] = (e < EE) ? ei[e] : 0;
        d[k] = (e < EE) ? ei[EE + e] : -1;
    }
    if (t < NBIN) hist[t] = 0;
    __syncthreads();
#pragma unroll
    for (int k = 0; k < EPT2; ++k)
        if (d[k] >= 0) atomicAdd(&hist[d[k] >> 8], 1);
    __syncthreads();
    int v = (t < NBIN) ? hist[t] : 0;
    sh[t] = v;
    __syncthreads();
    for (int off = 1; off < 256; off <<= 1) {
        int u = (t >= off) ? sh[t - off] : 0;
        __syncthreads();
        sh[t] += u;
        __syncthreads();
    }
    if (t < NBIN) { lofs[t] = sh[t] - v; cur[t] = sh[t] - v; }
    if (t == 0) lofs[NBIN] = nE;
    if (t < NBIN) sstart[t] = binbase[t] + histB[t * CB + blockIdx.x];
    __syncthreads();
#pragma unroll
    for (int k = 0; k < EPT2; ++k)
        if (d[k] >= 0) {
            int b = d[k] >> 8;
            int pos = atomicAdd(&cur[b], 1);
            buf[pos] = s[k] | ((d[k] & 0xFF) << 16);
        }
    __syncthreads();
    for (int i = t; i < nE; i += 256) {
        int blo = 0, bhi = NBIN;                 // find bin: lofs[b] <= i < lofs[b+1]
        while (bhi - blo > 1) {
            int mid = (blo + bhi) >> 1;
            if (lofs[mid] <= i) blo = mid; else bhi = mid;
        }
        packed[sstart[blo] + (i - lofs[blo])] = buf[i];
    }
}

// ---- 2: per-bin exact CSR (rp, dinv, col) — block owns its col window ---

__global__ __launch_bounds__(256) void k_csr(const int* __restrict__ packed,
                                             const int* __restrict__ binbase,
                                             int* __restrict__ rp,
                                             float* __restrict__ dinv,
                                             int* __restrict__ col) {
    __shared__ int h256[256];
    __shared__ int excl[256];
    __shared__ int cur[256];
    __shared__ int sh[256];
    int t = threadIdx.x;
    int b = blockIdx.x;
    int base = binbase[b];
    int nE = binbase[b + 1] - base;

    h256[t] = 0;
    __syncthreads();
    for (int i = t; i < nE; i += 256)
        atomicAdd(&h256[(packed[base + i] >> 16) & 0xFF], 1);
    __syncthreads();
    int v = h256[t];
    sh[t] = v;
    __syncthreads();
    for (int off = 1; off < 256; off <<= 1) {
        int u = (t >= off) ? sh[t - off] : 0;
        __syncthreads();
        sh[t] += u;
        __syncthreads();
    }
    excl[t] = sh[t] - v;
    cur[t] = sh[t] - v;
    int node = b * 256 + t;
    if (node <= NN) rp[node] = base + excl[t];   // node==NN lands on EE
    if (node < NN) dinv[node] = rsqrtf((float)(h256[t] + 1));  // +1 self-loop
    __syncthreads();
    for (int i = t; i < nE; i += 256) {
        int pv = packed[base + i];
        int pos = atomicAdd(&cur[(pv >> 16) & 0xFF], 1);
        col[base + pos] = pv & 0xFFFF;
    }
}

// ---- 3: x_h[s] = fp16(dinv[s] * x[s])  (one-time, layer-1 input) ---------

__global__ void k_cvt(const float* __restrict__ x, const float* __restrict__ dinv,
                      __half* __restrict__ xh) {
    int i = blockIdx.x * blockDim.x + threadIdx.x;   // half8 index
    if (i < NN * 12) {
        int row = i / 12;
        float sc = dinv[row];
        const float4* xx = (const float4*)x;
        float4 f0 = xx[i * 2], f1 = xx[i * 2 + 1];
        __half h[8];
        h[0] = __float2half_rn(sc * f0.x); h[1] = __float2half_rn(sc * f0.y);
        h[2] = __float2half_rn(sc * f0.z); h[3] = __float2half_rn(sc * f0.w);
        h[4] = __float2half_rn(sc * f1.x); h[5] = __float2half_rn(sc * f1.y);
        h[6] = __float2half_rn(sc * f1.z); h[7] = __float2half_rn(sc * f1.w);
        ((uint4*)xh)[i] = *(uint4*)h;
    }
}

// ---- 4: fused layer = gather(agg) -> LDS -> @W + b -> relu ----------------
// v[d] = dinv[d]*(sum_{s in in(d)} xh[s] + xh[d]);  out = relu(v @ W + b).
// FINAL=0: write acth[d] = fp16(dinv[d]*out). FINAL=1: write f32 out.
// W staged in LDS as fp16; 8-wide gather unroll for memory-level parallelism.

template <int FINAL>
__global__ __launch_bounds__(384, 4) void k_fused(const __half* __restrict__ xh,
                                                  const int* __restrict__ rp,
                                                  const int* __restrict__ col,
                                                  const float* __restrict__ dinv,
                                                  const float* __restrict__ W,
                                                  const float* __restrict__ b,
                                                  __half* __restrict__ acth,
                                                  float* __restrict__ outf) {
    __shared__ __half Wl[DD * DD];    // fp16 W, row-major (18432 B)
    __shared__ float Al[32][100];     // +4 pad (12800 B)
    int t = threadIdx.x;
    for (int i = t; i < DD * DD / 8; i += 384) {
        const float4* ww = (const float4*)W;
        float4 f0 = ww[i * 2], f1 = ww[i * 2 + 1];
        __half h[8];
        h[0] = __float2half_rn(f0.x); h[1] = __float2half_rn(f0.y);
        h[2] = __float2half_rn(f0.z); h[3] = __float2half_rn(f0.w);
        h[4] = __float2half_rn(f1.x); h[5] = __float2half_rn(f1.y);
        h[6] = __float2half_rn(f1.z); h[7] = __float2half_rn(f1.w);
        ((uint4*)Wl)[i] = *(uint4*)h;
    }

    int c  = t % 12;                  // half8 column
    int ny = t / 12;                  // 0..31
    int d = blockIdx.x * 32 + ny;
    const uint4* h4 = (const uint4*)xh;   // row stride 12

    if (d < NN) {
        union U { uint4 u; __half2 h[4]; };
        float2 aA[4] = {{0,0},{0,0},{0,0},{0,0}};
        float2 aB[4] = {{0,0},{0,0},{0,0},{0,0}};
        int j0 = rp[d], j1 = rp[d + 1];
        int j = j0;
        for (; j + 7 < j1; j += 8) {     // 8 independent 16B loads in flight
            int s0 = col[j],   s1 = col[j+1], s2 = col[j+2], s3 = col[j+3];
            int s4 = col[j+4], s5 = col[j+5], s6 = col[j+6], s7 = col[j+7];
            U v0, v1, v2, v3, v4, v5, v6, v7;
            v0.u = h4[s0 * 12 + c];
            v1.u = h4[s1 * 12 + c];
            v2.u = h4[s2 * 12 + c];
            v3.u = h4[s3 * 12 + c];
            v4.u = h4[s4 * 12 + c];
            v5.u = h4[s5 * 12 + c];
            v6.u = h4[s6 * 12 + c];
            v7.u = h4[s7 * 12 + c];
#pragma unroll
            for (int k = 0; k < 4; ++k) {
                float2 f0 = __half22float2(v0.h[k]);
                float2 f1 = __half22float2(v1.h[k]);
                float2 f2 = __half22float2(v2.h[k]);
                float2 f3 = __half22float2(v3.h[k]);
                float2 f4 = __half22float2(v4.h[k]);
                float2 f5 = __half22float2(v5.h[k]);
                float2 f6 = __half22float2(v6.h[k]);
                float2 f7 = __half22float2(v7.h[k]);
                aA[k].x += (f0.x + f1.x) + (f4.x + f5.x);
                aA[k].y += (f0.y + f1.y) + (f4.y + f5.y);
                aB[k].x += (f2.x + f3.x) + (f6.x + f7.x);
                aB[k].y += (f2.y + f3.y) + (f6.y + f7.y);
            }
        }
        for (; j + 3 < j1; j += 4) {
            int s0 = col[j], s1 = col[j+1], s2 = col[j+2], s3 = col[j+3];
            U v0, v1, v2, v3;
            v0.u = h4[s0 * 12 + c];
            v1.u = h4[s1 * 12 + c];
            v2.u = h4[s2 * 12 + c];
            v3.u = h4[s3 * 12 + c];
#pragma unroll
            for (int k = 0; k < 4; ++k) {
                float2 f0 = __half22float2(v0.h[k]);
                float2 f1 = __half22float2(v1.h[k]);
                float2 f2 = __half22float2(v2.h[k]);
                float2 f3 = __half22float2(v3.h[k]);
                aA[k].x += f0.x + f1.x; aA[k].y += f0.y + f1.y;
                aB[k].x += f2.x + f3.x; aB[k].y += f2.y + f3.y;
            }
        }
        for (; j < j1; ++j) {
            U v; v.u = h4[col[j] * 12 + c];
#pragma unroll
            for (int k = 0; k < 4; ++k) {
                float2 f = __half22float2(v.h[k]);
                aA[k].x += f.x; aA[k].y += f.y;
            }
        }
        U self; self.u = h4[d * 12 + c];    // self-loop (pre-scaled by dinv[d])
        float dd = dinv[d];
        float v[8];
#pragma unroll
        for (int k = 0; k < 4; ++k) {
            float2 fs = __half22float2(self.h[k]);
            v[2*k]   = dd * (aA[k].x + aB[k].x + fs.x);
            v[2*k+1] = dd * (aA[k].y + aB[k].y + fs.y);
        }
        *(float4*)&Al[ny][c * 8]     = make_float4(v[0], v[1], v[2], v[3]);
        *(float4*)&Al[ny][c * 8 + 4] = make_float4(v[4], v[5], v[6], v[7]);
    }
    __syncthreads();

    // Phase B: out_tile = Al @ W + b, relu, write.
    int tx = t % 24;                  // col4 group
    int ry = t / 24;                  // rows ry, ry+16
    int c0 = tx * 4;
    float a0x = 0.f, a0y = 0.f, a0z = 0.f, a0w = 0.f;
    float a1x = 0.f, a1y = 0.f, a1z = 0.f, a1w = 0.f;
#pragma unroll 8
    for (int k = 0; k < DD; ++k) {
        uint2 wv = *(const uint2*)&Wl[k * DD + c0];   // 4 halves
        const __half2* wh = (const __half2*)&wv;
        float2 w01 = __half22float2(wh[0]);
        float2 w23 = __half22float2(wh[1]);
        float r0 = Al[ry][k];
        float r1 = Al[ry + 16][k];
        a0x += r0 * w01.x; a0y += r0 * w01.y; a0z += r0 * w23.x; a0w += r0 * w23.y;
        a1x += r1 * w01.x; a1y += r1 * w01.y; a1z += r1 * w23.x; a1w += r1 * w23.y;
    }
    float4 bb = *(const float4*)&b[c0];
    int g0 = blockIdx.x * 32 + ry;
    int g1 = g0 + 16;
    float r0x = fmaxf(a0x + bb.x, 0.f), r0y = fmaxf(a0y + bb.y, 0.f);
    float r0z = fmaxf(a0z + bb.z, 0.f), r0w = fmaxf(a0w + bb.w, 0.f);
    float r1x = fmaxf(a1x + bb.x, 0.f), r1y = fmaxf(a1y + bb.y, 0.f);
    float r1z = fmaxf(a1z + bb.z, 0.f), r1w = fmaxf(a1w + bb.w, 0.f);
    if (g0 < NN) {
        if (FINAL) {
            *(float4*)&outf[g0 * DD + c0] = make_float4(r0x, r0y, r0z, r0w);
        } else {
            float sc = dinv[g0];
            __half h[4];
            h[0] = __float2half_rn(sc * r0x); h[1] = __float2half_rn(sc * r0y);
            h[2] = __float2half_rn(sc * r0z); h[3] = __float2half_rn(sc * r0w);
            *(uint2*)&acth[g0 * DD + c0] = *(uint2*)h;
        }
    }
    if (g1 < NN) {
        if (FINAL) {
            *(float4*)&outf[g1 * DD + c0] = make_float4(r1x, r1y, r1z, r1w);
        } else {
            float sc = dinv[g1];
            __half h[4];
            h[0] = __float2half_rn(sc * r1x); h[1] = __float2half_rn(sc * r1y);
            h[2] = __float2half_rn(sc * r1z); h[3] = __float2half_rn(sc * r1w);
            *(uint2*)&acth[g1 * DD + c0] = *(uint2*)h;
        }
    }
}

// ----------------------------------------------------------------------------

extern "C" void kernel_launch(void* const* d_in, const int* in_sizes, int n_in,
                              void* d_out, int out_size, void* d_ws, size_t ws_size,
                              hipStream_t stream) {
    const float* x  = (const float*)d_in[0];
    const int*   ei = (const int*)d_in[1];
    const float* W1 = (const float*)d_in[2];
    const float* b1 = (const float*)d_in[3];
    const float* W2 = (const float*)d_in[4];
    const float* b2 = (const float*)d_in[5];
    float* out = (float*)d_out;

    // Workspace (~23.0 MB): histB, binTot, binbase, rp, dinv, col, bufA, bufB.
    // packed[] aliases bufA (EE ints = 3.2 MB <= 9.6 MB; dead before k_cvt).
    char* p = (char*)d_ws;
    int*   histB   = (int*)p;   p += ((size_t)NBIN * CB * 4 + 255) & ~(size_t)255;
    int*   binTot  = (int*)p;   p += ((size_t)NBIN * 4 + 255) & ~(size_t)255;
    int*   binbase = (int*)p;   p += ((size_t)(NBIN + 1) * 4 + 255) & ~(size_t)255;
    int*   rp      = (int*)p;   p += ((size_t)(NN + 1) * 4 + 255) & ~(size_t)255;
    float* dinv    = (float*)p; p += ((size_t)NN * 4 + 255) & ~(size_t)255;
    int*   col     = (int*)p;   p += ((size_t)EE * 4 + 255) & ~(size_t)255;
    __half* bufA   = (__half*)p; p += ((size_t)NN * DD * 2 + 255) & ~(size_t)255;
    __half* bufB   = (__half*)p;                  // N*D halves (9.6 MB)
    int*   packed  = (int*)bufA;                  // EE ints, alias

    // ---- CSR build (no global atomics, no serial scans, separate launches) ----
    k_hist<<<CB, 256, 0, stream>>>(ei, histB);
    k_scan_bins<<<NBIN, 256, 0, stream>>>(histB, binTot);
    k_scan_tot<<<1, 256, 0, stream>>>(binTot, binbase);
    k_scatter_bins<<<CB, 256, 0, stream>>>(ei, histB, binbase, packed);
    k_csr<<<NBIN, 256, 0, stream>>>(packed, binbase, rp, dinv, col);

    // ---- x_h = fp16(dinv .* x) ----
    k_cvt<<<(NN * 12 + 255) / 256, 256, 0, stream>>>(x, dinv, bufA);

    // ---- layer 1 (fused): bufB = fp16(dinv .* relu(agg(bufA) @ W1 + b1)) ----
    k_fused<0><<<(NN + 31) / 32, 384, 0, stream>>>(bufA, rp, col, dinv, W1, b1,
                                                   bufB, nullptr);

    // ---- layer 2 (fused): d_out = relu(agg(bufB) @ W2 + b2) ----
    k_fused<1><<<(NN + 31) / 32, 384, 0, stream>>>(bufB, rp, col, dinv, W2, b2,
                                                   nullptr, out);
}